// Round 3
// baseline (347.392 us; speedup 1.0000x reference)
//
#include <hip/hip_runtime.h>
#include <stdint.h>

#define B_ 2
#define T_ 2048
#define C_ 2048
#define H_ 16
#define D_ 128
#define W_ 512
#define M_ (B_*T_)      // 4096
#define N1_ (3*C_)      // 6144

typedef short bf16x8 __attribute__((ext_vector_type(8)));
typedef unsigned short u16x8 __attribute__((ext_vector_type(8)));
typedef float f32x4 __attribute__((ext_vector_type(4)));

__device__ __forceinline__ unsigned short f2bf(float f) {
  union { float f; unsigned u; } v; v.f = f;
  unsigned r = v.u + 0x7fffu + ((v.u >> 16) & 1u);
  return (unsigned short)(r >> 16);
}
__device__ __forceinline__ float bf2f(unsigned short b) {
  union { unsigned u; float f; } v; v.u = ((unsigned)b) << 16;
  return v.f;
}

__device__ __forceinline__ void gload_lds16(const void* g, void* l) {
  __builtin_amdgcn_global_load_lds((const __attribute__((address_space(1))) void*)g,
                                   (__attribute__((address_space(3))) void*)l, 16, 0, 0);
}

// ---------- fp32 -> bf16 convert ----------
__global__ void k_cvt(const float* __restrict__ s, unsigned short* __restrict__ d, int n) {
  int i = (blockIdx.x * blockDim.x + threadIdx.x) * 8;
  if (i >= n) return;
  float4 a = *(const float4*)(s + i);
  float4 b = *(const float4*)(s + i + 4);
  u16x8 o;
  o[0]=f2bf(a.x); o[1]=f2bf(a.y); o[2]=f2bf(a.z); o[3]=f2bf(a.w);
  o[4]=f2bf(b.x); o[5]=f2bf(b.y); o[6]=f2bf(b.z); o[7]=f2bf(b.w);
  *(u16x8*)(d + i) = o;
}

// ---------- transpose + convert: src [R][Cc] f32 -> dst [Cc][R] bf16 ----------
__global__ void k_tcvt(const float* __restrict__ s, unsigned short* __restrict__ d, int R, int Cc) {
  __shared__ float tile[32][33];
  int c0 = blockIdx.x * 32, r0 = blockIdx.y * 32;
  int tx = threadIdx.x & 31, ty = threadIdx.x >> 5;
  #pragma unroll
  for (int j = 0; j < 32; j += 8) tile[ty + j][tx] = s[(size_t)(r0 + ty + j) * Cc + c0 + tx];
  __syncthreads();
  #pragma unroll
  for (int j = 0; j < 32; j += 8) d[(size_t)(c0 + ty + j) * R + r0 + tx] = f2bf(tile[tx][ty + j]);
}

// ---------- 256xBN 8-phase GEMM: C = A[M][K] * Bt[N][K]^T ----------
// LDS: [parity][khalf][rows][32 k] bf16, st_16x32 XOR swizzle (byte5 ^= byte9).

template<int ROWS>
__device__ __forceinline__ void stage_half(const unsigned short* __restrict__ gbase,
                                           int row0, int K, int kt, int kh,
                                           unsigned short* region, int tid, int sw) {
  const char* gsrc = (const char*)(gbase + (size_t)row0 * K + kt * 64 + kh * 32);
  {
    int o = tid * 16, s = o ^ sw;
    gload_lds16(gsrc + (size_t)(s >> 6) * (K * 2) + (s & 63), (char*)region + o);
  }
  if (ROWS == 256) {
    int o = (512 + tid) * 16, s = o ^ sw;
    gload_lds16(gsrc + (size_t)(s >> 6) * (K * 2) + (s & 63), (char*)region + o);
  } else if (ROWS == 192) {
    if (tid < 256) {
      int o = (512 + tid) * 16, s = o ^ sw;
      gload_lds16(gsrc + (size_t)(s >> 6) * (K * 2) + (s & 63), (char*)region + o);
    }
  }
}

template<int BN, bool F32OUT>
__global__ __launch_bounds__(512, 2) void k_gemm8(const unsigned short* __restrict__ A,
                                                  const unsigned short* __restrict__ Bt,
                                                  void* __restrict__ Cp,
                                                  int Ntot, int K) {
  constexpr int NBF = BN / 64;            // B fragments per wave
  __shared__ unsigned short As[2][2][256 * 32];
  __shared__ unsigned short Bs[2][2][BN * 32];
  const int tid = threadIdx.x, lane = tid & 63, wv = tid >> 6;
  const int wm = wv >> 2, wn = wv & 3;
  const int lr = lane & 15, lg = lane >> 4;
  const int sw = tid & 32;                // stage-side pre-swizzle (bit9 of o == bit5 of tid*16 idx)
  // per-thread constant fragment offset: XOR term is lane-constant ((lr&8)<<2)
  const int fofs = lr * 64 + ((lg * 16) ^ ((lr & 8) << 2));
  const int aoff = wm * 128 * 64 + fofs;  // bytes within A region
  const int boff = wn * (BN / 4) * 64 + fofs;

  // bijective XCD-aware block swizzle (m204)
  const int nwg = gridDim.x;
  const int nbx = Ntot / BN;
  const int q = nwg >> 3, r = nwg & 7;
  const int xcd = blockIdx.x & 7, off = blockIdx.x >> 3;
  const int bid = (xcd < r ? xcd * (q + 1) : r * (q + 1) + (xcd - r) * q) + off;
  const int bm0 = (bid / nbx) << 8;
  const int bn0 = (bid % nbx) * BN;

  f32x4 acc[8][NBF];
  #pragma unroll
  for (int i = 0; i < 8; ++i)
    #pragma unroll
    for (int j = 0; j < NBF; ++j)
      #pragma unroll
      for (int e = 0; e < 4; ++e) acc[i][j][e] = 0.f;

  const int NT = K >> 6;

  // prologue: tile0 fully, then tile1 (B0,A0,B1)
  stage_half<256>(A,  bm0, K, 0, 0, As[0][0], tid, sw);
  stage_half<BN >(Bt, bn0, K, 0, 0, Bs[0][0], tid, sw);
  stage_half<BN >(Bt, bn0, K, 0, 1, Bs[0][1], tid, sw);
  stage_half<256>(A,  bm0, K, 0, 1, As[0][1], tid, sw);
  stage_half<BN >(Bt, bn0, K, 1, 0, Bs[1][0], tid, sw);
  stage_half<256>(A,  bm0, K, 1, 0, As[1][0], tid, sw);
  stage_half<BN >(Bt, bn0, K, 1, 1, Bs[1][1], tid, sw);
  if (BN == 192 && wv < 4) asm volatile("s_waitcnt vmcnt(6)" ::: "memory");
  else                     asm volatile("s_waitcnt vmcnt(4)" ::: "memory");
  __builtin_amdgcn_s_barrier();

  bf16x8 af[4], bfr[NBF];
  #pragma unroll 2
  for (int t = 0; t < NT; ++t) {
    const int p = t & 1;
    const char* Ar0 = (const char*)As[p][0];
    const char* Ar1 = (const char*)As[p][1];
    const char* Br0 = (const char*)Bs[p][0];
    const char* Br1 = (const char*)Bs[p][1];

    // ---- phase 0: stage (t+1).A-kh1; read B ks0 + A rows0-3 ks0; 4*NBF MFMA ----
    if (t + 1 < NT) stage_half<256>(A, bm0, K, t + 1, 1, As[p ^ 1][1], tid, sw);
    #pragma unroll
    for (int j = 0; j < NBF; ++j) bfr[j] = *(const bf16x8*)(Br0 + boff + j * 1024);
    #pragma unroll
    for (int i = 0; i < 4; ++i) af[i] = *(const bf16x8*)(Ar0 + aoff + i * 1024);
    __builtin_amdgcn_s_barrier();
    asm volatile("s_waitcnt lgkmcnt(0)" ::: "memory");
    __builtin_amdgcn_sched_barrier(0);
    __builtin_amdgcn_s_setprio(1);
    #pragma unroll
    for (int i = 0; i < 4; ++i)
      #pragma unroll
      for (int j = 0; j < NBF; ++j)
        acc[i][j] = __builtin_amdgcn_mfma_f32_16x16x32_bf16(af[i], bfr[j], acc[i][j], 0, 0, 0);
    __builtin_amdgcn_s_setprio(0);
    __builtin_amdgcn_s_barrier();

    // ---- phase 1: stage (t+2).B-kh0; read A rows4-7 ks0 ----
    if (t + 2 < NT) stage_half<BN>(Bt, bn0, K, t + 2, 0, Bs[p][0], tid, sw);
    #pragma unroll
    for (int i = 0; i < 4; ++i) af[i] = *(const bf16x8*)(Ar0 + aoff + (i + 4) * 1024);
    __builtin_amdgcn_s_barrier();
    asm volatile("s_waitcnt lgkmcnt(0)" ::: "memory");
    __builtin_amdgcn_sched_barrier(0);
    __builtin_amdgcn_s_setprio(1);
    #pragma unroll
    for (int i = 0; i < 4; ++i)
      #pragma unroll
      for (int j = 0; j < NBF; ++j)
        acc[i + 4][j] = __builtin_amdgcn_mfma_f32_16x16x32_bf16(af[i], bfr[j], acc[i + 4][j], 0, 0, 0);
    __builtin_amdgcn_s_setprio(0);
    __builtin_amdgcn_s_barrier();

    // ---- phase 2: stage (t+2).A-kh0; read B ks1 + A rows0-3 ks1 ----
    if (t + 2 < NT) stage_half<256>(A, bm0, K, t + 2, 0, As[p][0], tid, sw);
    #pragma unroll
    for (int j = 0; j < NBF; ++j) bfr[j] = *(const bf16x8*)(Br1 + boff + j * 1024);
    #pragma unroll
    for (int i = 0; i < 4; ++i) af[i] = *(const bf16x8*)(Ar1 + aoff + i * 1024);
    __builtin_amdgcn_s_barrier();
    asm volatile("s_waitcnt lgkmcnt(0)" ::: "memory");
    __builtin_amdgcn_sched_barrier(0);
    __builtin_amdgcn_s_setprio(1);
    #pragma unroll
    for (int i = 0; i < 4; ++i)
      #pragma unroll
      for (int j = 0; j < NBF; ++j)
        acc[i][j] = __builtin_amdgcn_mfma_f32_16x16x32_bf16(af[i], bfr[j], acc[i][j], 0, 0, 0);
    __builtin_amdgcn_s_setprio(0);
    __builtin_amdgcn_s_barrier();

    // ---- phase 3: stage (t+2).B-kh1; read A rows4-7 ks1; vmcnt; barrier ----
    if (t + 2 < NT) stage_half<BN>(Bt, bn0, K, t + 2, 1, Bs[p][1], tid, sw);
    #pragma unroll
    for (int i = 0; i < 4; ++i) af[i] = *(const bf16x8*)(Ar1 + aoff + (i + 4) * 1024);
    __builtin_amdgcn_s_barrier();
    asm volatile("s_waitcnt lgkmcnt(0)" ::: "memory");
    __builtin_amdgcn_sched_barrier(0);
    __builtin_amdgcn_s_setprio(1);
    #pragma unroll
    for (int i = 0; i < 4; ++i)
      #pragma unroll
      for (int j = 0; j < NBF; ++j)
        acc[i + 4][j] = __builtin_amdgcn_mfma_f32_16x16x32_bf16(af[i], bfr[j], acc[i + 4][j], 0, 0, 0);
    __builtin_amdgcn_s_setprio(0);
    if (t < NT - 3) {
      if (BN == 192 && wv < 4) asm volatile("s_waitcnt vmcnt(6)" ::: "memory");
      else                     asm volatile("s_waitcnt vmcnt(4)" ::: "memory");
    } else {
      asm volatile("s_waitcnt vmcnt(0)" ::: "memory");
    }
    __builtin_amdgcn_s_barrier();
  }

  #pragma unroll
  for (int i = 0; i < 8; ++i)
    #pragma unroll
    for (int j = 0; j < NBF; ++j) {
      int m = bm0 + wm * 128 + i * 16 + lg * 4;
      int n = bn0 + wn * (BN / 4) + j * 16 + lr;
      #pragma unroll
      for (int e = 0; e < 4; ++e) {
        if (F32OUT) ((float*)Cp)[(size_t)(m + e) * Ntot + n] = acc[i][j][e];
        else ((unsigned short*)Cp)[(size_t)(m + e) * Ntot + n] = f2bf(acc[i][j][e]);
      }
    }
}

// ---------- reorg: RoPE(q,k) -> (B,H,T,D); v -> v_t (B,H,D,T) ----------
__global__ __launch_bounds__(256) void k_reorg(const unsigned short* __restrict__ qkv,
                        const float* __restrict__ fcos, const float* __restrict__ fsin,
                        unsigned short* __restrict__ q_r, unsigned short* __restrict__ k_r,
                        unsigned short* __restrict__ v_t) {
  const int bh = blockIdx.x, b = bh >> 4, h = bh & 15;
  const int t0 = blockIdx.y * 64;
  const int tid = threadIdx.x;
  __shared__ unsigned short vt[64][136];
  #pragma unroll
  for (int p = 0; p < 4; ++p) {
    int idx = p * 256 + tid;
    int tl = idx >> 4, sg = idx & 15;
    int t = t0 + tl, d0 = sg * 8;
    float sgn = (d0 < 64) ? -1.f : 1.f;
    float4 c0v = *(const float4*)(fcos + t * D_ + d0);
    float4 c1v = *(const float4*)(fcos + t * D_ + d0 + 4);
    float4 s0v = *(const float4*)(fsin + t * D_ + d0);
    float4 s1v = *(const float4*)(fsin + t * D_ + d0 + 4);
    float cs[8] = {c0v.x,c0v.y,c0v.z,c0v.w,c1v.x,c1v.y,c1v.z,c1v.w};
    float sn[8] = {s0v.x,s0v.y,s0v.z,s0v.w,s1v.x,s1v.y,s1v.z,s1v.w};
    #pragma unroll
    for (int w = 0; w < 2; ++w) {
      const unsigned short* src = qkv + (size_t)(b*T_ + t) * N1_ + w*C_ + h*D_;
      u16x8 a  = *(const u16x8*)(src + d0);
      u16x8 pr = *(const u16x8*)(src + (d0 ^ 64));
      u16x8 o;
      #pragma unroll
      for (int e = 0; e < 8; ++e)
        o[e] = f2bf(bf2f(a[e]) * cs[e] + sgn * bf2f(pr[e]) * sn[e]);
      unsigned short* dst = (w ? k_r : q_r) + (size_t)((b*H_ + h)*T_ + t) * D_ + d0;
      *(u16x8*)dst = o;
    }
    const unsigned short* vsrc = qkv + (size_t)(b*T_ + t) * N1_ + 2*C_ + h*D_ + d0;
    *(u16x8*)&vt[tl][d0] = *(const u16x8*)vsrc;
  }
  __syncthreads();
  #pragma unroll
  for (int p = 0; p < 4; ++p) {
    int idx = p * 256 + tid;
    int sg = idx & 7, d = idx >> 3;
    u16x8 o;
    #pragma unroll
    for (int e = 0; e < 8; ++e) o[e] = vt[sg*8 + e][d];
    *(u16x8*)(v_t + (size_t)((b*H_ + h)*D_ + d) * T_ + t0 + sg*8) = o;
  }
}

// ---------- sliding-window flash attention ----------
__global__ __launch_bounds__(256) void k_attn(const unsigned short* __restrict__ q_r,
                       const unsigned short* __restrict__ k_r,
                       const unsigned short* __restrict__ v_t,
                       unsigned short* __restrict__ y) {
  const int bh = blockIdx.x, b = bh >> 4, h = bh & 15;
  const int q0 = blockIdx.y * 64;
  const int tid = threadIdx.x, lane = tid & 63, wv = tid >> 6;
  const int lr = lane & 15, lg = lane >> 4;

  __shared__ unsigned short Ks[64][136];
  __shared__ unsigned short Vs[128][72];
  __shared__ unsigned short Ps[4][16][80];

  const size_t bhT = (size_t)(b*H_ + h) * T_;
  const unsigned short* qbase = q_r + (bhT + q0 + wv*16 + lr) * D_;
  bf16x8 qf[4];
  #pragma unroll
  for (int kk = 0; kk < 4; ++kk) qf[kk] = *(const bf16x8*)(qbase + kk*32 + lg*8);

  f32x4 o[8];
  #pragma unroll
  for (int i = 0; i < 8; ++i)
    #pragma unroll
    for (int e = 0; e < 4; ++e) o[i][e] = 0.f;
  float m_run[4], l_sum[4];
  #pragma unroll
  for (int e = 0; e < 4; ++e) { m_run[e] = -1e30f; l_sum[e] = 0.f; }

  const int i_min = q0 + wv*16, i_max = i_min + 15;
  int kt_lo = q0 - (W_ - 1); if (kt_lo < 0) kt_lo = 0; kt_lo &= ~63;
  const float scale = 0.08838834764831845f;

  for (int kt = kt_lo; kt < q0 + 64; kt += 64) {
    #pragma unroll
    for (int p = 0; p < 4; ++p) {
      int idx = p*256 + tid;
      int row = idx >> 4, sg = idx & 15;
      *(u16x8*)&Ks[row][sg*8] = *(const u16x8*)(k_r + (bhT + kt + row) * D_ + sg*8);
    }
    #pragma unroll
    for (int p = 0; p < 4; ++p) {
      int idx = p*256 + tid;
      int d = idx >> 3, sg = idx & 7;
      *(u16x8*)&Vs[d][sg*8] = *(const u16x8*)(v_t + ((size_t)(b*H_+h)*D_ + d) * T_ + kt + sg*8);
    }
    __syncthreads();

    if (kt <= i_max && kt + 63 >= i_min - (W_ - 1)) {
      f32x4 s[4];
      #pragma unroll
      for (int ct = 0; ct < 4; ++ct)
        #pragma unroll
        for (int e = 0; e < 4; ++e) s[ct][e] = 0.f;
      #pragma unroll
      for (int kk = 0; kk < 4; ++kk) {
        #pragma unroll
        for (int ct = 0; ct < 4; ++ct) {
          bf16x8 kf = *(const bf16x8*)((const char*)&Ks[ct*16 + lr][0] + kk*64 + lg*16);
          s[ct] = __builtin_amdgcn_mfma_f32_16x16x32_bf16(qf[kk], kf, s[ct], 0, 0, 0);
        }
      }
      #pragma unroll
      for (int e = 0; e < 4; ++e) {
        int i = i_min + lg*4 + e;
        float sv[4];
        float rm = -1e30f;
        #pragma unroll
        for (int ct = 0; ct < 4; ++ct) {
          int j = kt + ct*16 + lr;
          bool ok = (j <= i) && (j > i - W_);
          sv[ct] = ok ? s[ct][e] * scale : -1e30f;
          rm = fmaxf(rm, sv[ct]);
        }
        #pragma unroll
        for (int msk = 1; msk < 16; msk <<= 1) rm = fmaxf(rm, __shfl_xor(rm, msk));
        float mnew = fmaxf(m_run[e], rm);
        float fac = __expf(m_run[e] - mnew);
        float rs = 0.f;
        #pragma unroll
        for (int ct = 0; ct < 4; ++ct) {
          float pv = (sv[ct] > -1e29f) ? __expf(sv[ct] - mnew) : 0.f;
          rs += pv;
          Ps[wv][lg*4 + e][ct*16 + lr] = f2bf(pv);
        }
        #pragma unroll
        for (int msk = 1; msk < 16; msk <<= 1) rs += __shfl_xor(rs, msk);
        l_sum[e] = l_sum[e] * fac + rs;
        m_run[e] = mnew;
        #pragma unroll
        for (int nt = 0; nt < 8; ++nt) o[nt][e] *= fac;
      }
      asm volatile("s_waitcnt lgkmcnt(0)" ::: "memory");
      #pragma unroll
      for (int kk = 0; kk < 2; ++kk) {
        bf16x8 pf = *(const bf16x8*)((const char*)&Ps[wv][lr][0] + kk*64 + lg*16);
        #pragma unroll
        for (int nt = 0; nt < 8; ++nt) {
          bf16x8 vf = *(const bf16x8*)((const char*)&Vs[nt*16 + lr][0] + kk*64 + lg*16);
          o[nt] = __builtin_amdgcn_mfma_f32_16x16x32_bf16(pf, vf, o[nt], 0, 0, 0);
        }
      }
    }
    __syncthreads();
  }

  #pragma unroll
  for (int nt = 0; nt < 8; ++nt) {
    #pragma unroll
    for (int e = 0; e < 4; ++e) {
      int t = q0 + wv*16 + lg*4 + e;
      int d = nt*16 + lr;
      y[(size_t)(b*T_ + t) * C_ + h*D_ + d] = f2bf(o[nt][e] / l_sum[e]);
    }
  }
}

extern "C" void kernel_launch(void* const* d_in, const int* in_sizes, int n_in,
                              void* d_out, int out_size, void* d_ws, size_t ws_size,
                              hipStream_t stream) {
  const float* x      = (const float*)d_in[0];
  const float* fcos   = (const float*)d_in[1];
  const float* fsin   = (const float*)d_in[2];
  const float* w_attn = (const float*)d_in[3];
  const float* w_proj = (const float*)d_in[4];
  float* out = (float*)d_out;

  char* ws = (char*)d_ws;
  unsigned short* x_bf = (unsigned short*)(ws);
  unsigned short* wa_t = (unsigned short*)(ws + 16777216ull);
  unsigned short* wp_t = (unsigned short*)(ws + 41943040ull);
  unsigned short* qkv  = (unsigned short*)(ws + 50331648ull);
  unsigned short* q_r  = (unsigned short*)(ws + 100663296ull);
  unsigned short* k_r  = (unsigned short*)(ws + 117440512ull);
  unsigned short* v_t  = (unsigned short*)(ws + 134217728ull);
  unsigned short* y_bf = x_bf;

  k_cvt<<<dim3(4096), dim3(256), 0, stream>>>(x, x_bf, M_*C_);
  k_tcvt<<<dim3(192, 64), dim3(256), 0, stream>>>(w_attn, wa_t, C_, N1_);
  k_tcvt<<<dim3(64, 64), dim3(256), 0, stream>>>(w_proj, wp_t, C_, C_);
  k_gemm8<192, false><<<dim3(512), dim3(512), 0, stream>>>(x_bf, wa_t, qkv, N1_, C_);
  k_reorg<<<dim3(32, 32), dim3(256), 0, stream>>>(qkv, fcos, fsin, q_r, k_r, v_t);
  k_attn<<<dim3(32, 32), dim3(256), 0, stream>>>(q_r, k_r, v_t, y_bf);
  k_gemm8<128, true><<<dim3(256), dim3(512), 0, stream>>>(y_bf, wp_t, out, C_, C_);
}

// Round 4
// 311.956 us; speedup vs baseline: 1.1136x; 1.1136x over previous
//
#include <hip/hip_runtime.h>
#include <stdint.h>

#define B_ 2
#define T_ 2048
#define C_ 2048
#define H_ 16
#define D_ 128
#define W_ 512
#define M_ (B_*T_)      // 4096
#define N1_ (3*C_)      // 6144

typedef short bf16x8 __attribute__((ext_vector_type(8)));
typedef unsigned short u16x8 __attribute__((ext_vector_type(8)));
typedef float f32x4 __attribute__((ext_vector_type(4)));

__device__ __forceinline__ unsigned short f2bf(float f) {
  union { float f; unsigned u; } v; v.f = f;
  unsigned r = v.u + 0x7fffu + ((v.u >> 16) & 1u);
  return (unsigned short)(r >> 16);
}
__device__ __forceinline__ float bf2f(unsigned short b) {
  union { unsigned u; float f; } v; v.u = ((unsigned)b) << 16;
  return v.f;
}

__device__ __forceinline__ void gload_lds16(const void* g, void* l) {
  __builtin_amdgcn_global_load_lds((const __attribute__((address_space(1))) void*)g,
                                   (__attribute__((address_space(3))) void*)l, 16, 0, 0);
}

// ---------- fp32 -> bf16 convert ----------
__global__ void k_cvt(const float* __restrict__ s, unsigned short* __restrict__ d, int n) {
  int i = (blockIdx.x * blockDim.x + threadIdx.x) * 8;
  if (i >= n) return;
  float4 a = *(const float4*)(s + i);
  float4 b = *(const float4*)(s + i + 4);
  u16x8 o;
  o[0]=f2bf(a.x); o[1]=f2bf(a.y); o[2]=f2bf(a.z); o[3]=f2bf(a.w);
  o[4]=f2bf(b.x); o[5]=f2bf(b.y); o[6]=f2bf(b.z); o[7]=f2bf(b.w);
  *(u16x8*)(d + i) = o;
}

// ---------- transpose + convert: src [R][Cc] f32 -> dst [Cc][R] bf16 ----------
__global__ void k_tcvt(const float* __restrict__ s, unsigned short* __restrict__ d, int R, int Cc) {
  __shared__ float tile[32][33];
  int c0 = blockIdx.x * 32, r0 = blockIdx.y * 32;
  int tx = threadIdx.x & 31, ty = threadIdx.x >> 5;
  #pragma unroll
  for (int j = 0; j < 32; j += 8) tile[ty + j][tx] = s[(size_t)(r0 + ty + j) * Cc + c0 + tx];
  __syncthreads();
  #pragma unroll
  for (int j = 0; j < 32; j += 8) d[(size_t)(c0 + ty + j) * R + r0 + tx] = f2bf(tile[tx][ty + j]);
}

// ---------- 256x256 4-phase GEMM, register-pipelined ds_reads ----------
// LDS: [parity][khalf][256 rows][32 k] bf16, st_16x32 XOR swizzle.
// Phase k's MFMA consumes fragments loaded during phase k-1 (reads overlap MFMA).
// Hazard ledger (per-tile t, parity p):
//   reads issued at ph3(t-1): Bs[p][0], As[p][0] r0-3  (consumed ph0)
//   reads at ph0: As[p][0] r4-7 (ph1); ph1: Bs[p][1], As[p][1] r0-3 (ph2);
//   ph2: As[p][1] r4-7 (ph3); ph3: next-tile Bs[p^1][0], As[p^1][0] r0-3.
//   Stage targets vs readers: ph1->Bs[p][0] (reads done by ph0 lgkm + barrier);
//   ph2->As[p][0] (done ph1); ph3->Bs[p][1] (done ph2); ph0->As[p^1][1]
//   (tile t-1's readers done before its ph3 barrier). All DMA-writes follow a
//   barrier that postdates their readers' lgkmcnt(0). vmcnt(4) before ph3's
//   next-tile reads completes t+1.{B0,A0,B1,A1} (leaves t+2.{B0,A0} in flight).
__device__ __forceinline__ void stage_half(const unsigned short* __restrict__ gbase,
                                           int row0, int K, int kt, int kh,
                                           unsigned short* region, int tid, int sw) {
  const char* gsrc = (const char*)(gbase + (size_t)row0 * K + kt * 64 + kh * 32);
  {
    int o = tid * 16, s = o ^ sw;
    gload_lds16(gsrc + (size_t)(s >> 6) * (K * 2) + (s & 63), (char*)region + o);
  }
  {
    int o = (512 + tid) * 16, s = o ^ sw;
    gload_lds16(gsrc + (size_t)(s >> 6) * (K * 2) + (s & 63), (char*)region + o);
  }
}

template<bool F32OUT>
__global__ __launch_bounds__(512, 2) void k_gemm8(const unsigned short* __restrict__ A,
                                                  const unsigned short* __restrict__ Bt,
                                                  void* __restrict__ Cp,
                                                  int Ntot, int K) {
  __shared__ unsigned short As[2][2][256 * 32];
  __shared__ unsigned short Bs[2][2][256 * 32];
  const int tid = threadIdx.x, lane = tid & 63, wv = tid >> 6;
  const int wm = wv >> 2, wn = wv & 3;
  const int lr = lane & 15, lg = lane >> 4;
  const int sw = tid & 32;
  const int fofs = lr * 64 + ((lg * 16) ^ ((lr & 8) << 2));
  const int aoff = wm * 128 * 64 + fofs;
  const int boff = wn * 64 * 64 + fofs;

  const int nwg = gridDim.x;
  const int nbx = Ntot >> 8;
  const int q = nwg >> 3, r = nwg & 7;
  const int xcd = blockIdx.x & 7, off = blockIdx.x >> 3;
  const int bid = (xcd < r ? xcd * (q + 1) : r * (q + 1) + (xcd - r) * q) + off;
  const int bm0 = (bid / nbx) << 8;
  const int bn0 = (bid % nbx) << 8;

  f32x4 acc[8][4];
  #pragma unroll
  for (int i = 0; i < 8; ++i)
    #pragma unroll
    for (int j = 0; j < 4; ++j)
      #pragma unroll
      for (int e = 0; e < 4; ++e) acc[i][j][e] = 0.f;

  const int NT = K >> 6;

  stage_half(A,  bm0, K, 0, 0, As[0][0], tid, sw);
  stage_half(Bt, bn0, K, 0, 0, Bs[0][0], tid, sw);
  stage_half(Bt, bn0, K, 0, 1, Bs[0][1], tid, sw);
  stage_half(A,  bm0, K, 0, 1, As[0][1], tid, sw);
  stage_half(Bt, bn0, K, 1, 0, Bs[1][0], tid, sw);
  stage_half(A,  bm0, K, 1, 0, As[1][0], tid, sw);
  stage_half(Bt, bn0, K, 1, 1, Bs[1][1], tid, sw);
  asm volatile("s_waitcnt vmcnt(4)" ::: "memory");
  __builtin_amdgcn_s_barrier();

  bf16x8 Xa[4], Xb[4], Ya[4];
  // preload tile0/ph0 operands
  #pragma unroll
  for (int j = 0; j < 4; ++j) Xb[j] = *(const bf16x8*)((const char*)Bs[0][0] + boff + j * 1024);
  #pragma unroll
  for (int i = 0; i < 4; ++i) Xa[i] = *(const bf16x8*)((const char*)As[0][0] + aoff + i * 1024);

  #pragma unroll 2
  for (int t = 0; t < NT; ++t) {
    const int p = t & 1;
    // ---- ph0: MFMA(acc0-3, Xa,Xb); load Ya=A[p][0]r4-7; stage (t+1).A1 ----
    asm volatile("s_waitcnt lgkmcnt(0)" ::: "memory");
    __builtin_amdgcn_sched_barrier(0);
    __builtin_amdgcn_s_setprio(1);
    #pragma unroll
    for (int i = 0; i < 4; ++i)
      #pragma unroll
      for (int j = 0; j < 4; ++j)
        acc[i][j] = __builtin_amdgcn_mfma_f32_16x16x32_bf16(Xa[i], Xb[j], acc[i][j], 0, 0, 0);
    __builtin_amdgcn_s_setprio(0);
    #pragma unroll
    for (int i = 0; i < 4; ++i) Ya[i] = *(const bf16x8*)((const char*)As[p][0] + aoff + (i + 4) * 1024);
    if (t + 1 < NT) stage_half(A, bm0, K, t + 1, 1, As[p ^ 1][1], tid, sw);
    __builtin_amdgcn_s_barrier();

    // ---- ph1: MFMA(acc4-7, Ya,Xb); load Xb=B[p][1], Xa=A[p][1]r0-3; stage (t+2).B0 ----
    asm volatile("s_waitcnt lgkmcnt(0)" ::: "memory");
    __builtin_amdgcn_sched_barrier(0);
    __builtin_amdgcn_s_setprio(1);
    #pragma unroll
    for (int i = 0; i < 4; ++i)
      #pragma unroll
      for (int j = 0; j < 4; ++j)
        acc[i + 4][j] = __builtin_amdgcn_mfma_f32_16x16x32_bf16(Ya[i], Xb[j], acc[i + 4][j], 0, 0, 0);
    __builtin_amdgcn_s_setprio(0);
    #pragma unroll
    for (int j = 0; j < 4; ++j) Xb[j] = *(const bf16x8*)((const char*)Bs[p][1] + boff + j * 1024);
    #pragma unroll
    for (int i = 0; i < 4; ++i) Xa[i] = *(const bf16x8*)((const char*)As[p][1] + aoff + i * 1024);
    if (t + 2 < NT) stage_half(Bt, bn0, K, t + 2, 0, Bs[p][0], tid, sw);
    __builtin_amdgcn_s_barrier();

    // ---- ph2: MFMA(acc0-3, Xa,Xb); load Ya=A[p][1]r4-7; stage (t+2).A0 ----
    asm volatile("s_waitcnt lgkmcnt(0)" ::: "memory");
    __builtin_amdgcn_sched_barrier(0);
    __builtin_amdgcn_s_setprio(1);
    #pragma unroll
    for (int i = 0; i < 4; ++i)
      #pragma unroll
      for (int j = 0; j < 4; ++j)
        acc[i][j] = __builtin_amdgcn_mfma_f32_16x16x32_bf16(Xa[i], Xb[j], acc[i][j], 0, 0, 0);
    __builtin_amdgcn_s_setprio(0);
    #pragma unroll
    for (int i = 0; i < 4; ++i) Ya[i] = *(const bf16x8*)((const char*)As[p][1] + aoff + (i + 4) * 1024);
    if (t + 2 < NT) stage_half(A, bm0, K, t + 2, 0, As[p][0], tid, sw);
    __builtin_amdgcn_s_barrier();

    // ---- ph3: MFMA(acc4-7, Ya,Xb); vmcnt; load next-tile X; stage (t+2).B1 ----
    asm volatile("s_waitcnt lgkmcnt(0)" ::: "memory");
    __builtin_amdgcn_sched_barrier(0);
    __builtin_amdgcn_s_setprio(1);
    #pragma unroll
    for (int i = 0; i < 4; ++i)
      #pragma unroll
      for (int j = 0; j < 4; ++j)
        acc[i + 4][j] = __builtin_amdgcn_mfma_f32_16x16x32_bf16(Ya[i], Xb[j], acc[i + 4][j], 0, 0, 0);
    __builtin_amdgcn_s_setprio(0);
    if (t < NT - 2) asm volatile("s_waitcnt vmcnt(4)" ::: "memory");
    else            asm volatile("s_waitcnt vmcnt(0)" ::: "memory");
    #pragma unroll
    for (int j = 0; j < 4; ++j) Xb[j] = *(const bf16x8*)((const char*)Bs[p ^ 1][0] + boff + j * 1024);
    #pragma unroll
    for (int i = 0; i < 4; ++i) Xa[i] = *(const bf16x8*)((const char*)As[p ^ 1][0] + aoff + i * 1024);
    if (t + 2 < NT) stage_half(Bt, bn0, K, t + 2, 1, Bs[p][1], tid, sw);
    __builtin_amdgcn_s_barrier();
  }
  asm volatile("s_waitcnt lgkmcnt(0)" ::: "memory");

  #pragma unroll
  for (int i = 0; i < 8; ++i)
    #pragma unroll
    for (int j = 0; j < 4; ++j) {
      int m = bm0 + wm * 128 + i * 16 + lg * 4;
      int n = bn0 + wn * 64 + j * 16 + lr;
      #pragma unroll
      for (int e = 0; e < 4; ++e) {
        if (F32OUT) ((float*)Cp)[(size_t)(m + e) * Ntot + n] = acc[i][j][e];
        else ((unsigned short*)Cp)[(size_t)(m + e) * Ntot + n] = f2bf(acc[i][j][e]);
      }
    }
}

// ---------- reorg: RoPE(q,k) -> (B,H,T,D); v -> v_t (B,H,D,T) ----------
__global__ __launch_bounds__(256) void k_reorg(const unsigned short* __restrict__ qkv,
                        const float* __restrict__ fcos, const float* __restrict__ fsin,
                        unsigned short* __restrict__ q_r, unsigned short* __restrict__ k_r,
                        unsigned short* __restrict__ v_t) {
  const int bh = blockIdx.x, b = bh >> 4, h = bh & 15;
  const int t0 = blockIdx.y * 64;
  const int tid = threadIdx.x;
  __shared__ unsigned short vt[64][136];
  #pragma unroll
  for (int p = 0; p < 4; ++p) {
    int idx = p * 256 + tid;
    int tl = idx >> 4, sg = idx & 15;
    int t = t0 + tl, d0 = sg * 8;
    float sgn = (d0 < 64) ? -1.f : 1.f;
    float4 c0v = *(const float4*)(fcos + t * D_ + d0);
    float4 c1v = *(const float4*)(fcos + t * D_ + d0 + 4);
    float4 s0v = *(const float4*)(fsin + t * D_ + d0);
    float4 s1v = *(const float4*)(fsin + t * D_ + d0 + 4);
    float cs[8] = {c0v.x,c0v.y,c0v.z,c0v.w,c1v.x,c1v.y,c1v.z,c1v.w};
    float sn[8] = {s0v.x,s0v.y,s0v.z,s0v.w,s1v.x,s1v.y,s1v.z,s1v.w};
    #pragma unroll
    for (int w = 0; w < 2; ++w) {
      const unsigned short* src = qkv + (size_t)(b*T_ + t) * N1_ + w*C_ + h*D_;
      u16x8 a  = *(const u16x8*)(src + d0);
      u16x8 pr = *(const u16x8*)(src + (d0 ^ 64));
      u16x8 o;
      #pragma unroll
      for (int e = 0; e < 8; ++e)
        o[e] = f2bf(bf2f(a[e]) * cs[e] + sgn * bf2f(pr[e]) * sn[e]);
      unsigned short* dst = (w ? k_r : q_r) + (size_t)((b*H_ + h)*T_ + t) * D_ + d0;
      *(u16x8*)dst = o;
    }
    const unsigned short* vsrc = qkv + (size_t)(b*T_ + t) * N1_ + 2*C_ + h*D_ + d0;
    *(u16x8*)&vt[tl][d0] = *(const u16x8*)vsrc;
  }
  __syncthreads();
  #pragma unroll
  for (int p = 0; p < 4; ++p) {
    int idx = p * 256 + tid;
    int sg = idx & 7, d = idx >> 3;
    u16x8 o;
    #pragma unroll
    for (int e = 0; e < 8; ++e) o[e] = vt[sg*8 + e][d];
    *(u16x8*)(v_t + (size_t)((b*H_ + h)*D_ + d) * T_ + t0 + sg*8) = o;
  }
}

// ---------- sliding-window flash attention ----------
__global__ __launch_bounds__(256) void k_attn(const unsigned short* __restrict__ q_r,
                       const unsigned short* __restrict__ k_r,
                       const unsigned short* __restrict__ v_t,
                       unsigned short* __restrict__ y) {
  const int bh = blockIdx.x, b = bh >> 4, h = bh & 15;
  const int q0 = blockIdx.y * 64;
  const int tid = threadIdx.x, lane = tid & 63, wv = tid >> 6;
  const int lr = lane & 15, lg = lane >> 4;

  __shared__ unsigned short Ks[64][136];
  __shared__ unsigned short Vs[128][72];
  __shared__ unsigned short Ps[4][16][80];

  const size_t bhT = (size_t)(b*H_ + h) * T_;
  const unsigned short* qbase = q_r + (bhT + q0 + wv*16 + lr) * D_;
  bf16x8 qf[4];
  #pragma unroll
  for (int kk = 0; kk < 4; ++kk) qf[kk] = *(const bf16x8*)(qbase + kk*32 + lg*8);

  f32x4 o[8];
  #pragma unroll
  for (int i = 0; i < 8; ++i)
    #pragma unroll
    for (int e = 0; e < 4; ++e) o[i][e] = 0.f;
  float m_run[4], l_sum[4];
  #pragma unroll
  for (int e = 0; e < 4; ++e) { m_run[e] = -1e30f; l_sum[e] = 0.f; }

  const int i_min = q0 + wv*16, i_max = i_min + 15;
  int kt_lo = q0 - (W_ - 1); if (kt_lo < 0) kt_lo = 0; kt_lo &= ~63;
  const float scale = 0.08838834764831845f;

  for (int kt = kt_lo; kt < q0 + 64; kt += 64) {
    #pragma unroll
    for (int p = 0; p < 4; ++p) {
      int idx = p*256 + tid;
      int row = idx >> 4, sg = idx & 15;
      *(u16x8*)&Ks[row][sg*8] = *(const u16x8*)(k_r + (bhT + kt + row) * D_ + sg*8);
    }
    #pragma unroll
    for (int p = 0; p < 4; ++p) {
      int idx = p*256 + tid;
      int d = idx >> 3, sg = idx & 7;
      *(u16x8*)&Vs[d][sg*8] = *(const u16x8*)(v_t + ((size_t)(b*H_+h)*D_ + d) * T_ + kt + sg*8);
    }
    __syncthreads();

    if (kt <= i_max && kt + 63 >= i_min - (W_ - 1)) {
      f32x4 s[4];
      #pragma unroll
      for (int ct = 0; ct < 4; ++ct)
        #pragma unroll
        for (int e = 0; e < 4; ++e) s[ct][e] = 0.f;
      #pragma unroll
      for (int kk = 0; kk < 4; ++kk) {
        #pragma unroll
        for (int ct = 0; ct < 4; ++ct) {
          bf16x8 kf = *(const bf16x8*)((const char*)&Ks[ct*16 + lr][0] + kk*64 + lg*16);
          s[ct] = __builtin_amdgcn_mfma_f32_16x16x32_bf16(qf[kk], kf, s[ct], 0, 0, 0);
        }
      }
      #pragma unroll
      for (int e = 0; e < 4; ++e) {
        int i = i_min + lg*4 + e;
        float sv[4];
        float rm = -1e30f;
        #pragma unroll
        for (int ct = 0; ct < 4; ++ct) {
          int j = kt + ct*16 + lr;
          bool ok = (j <= i) && (j > i - W_);
          sv[ct] = ok ? s[ct][e] * scale : -1e30f;
          rm = fmaxf(rm, sv[ct]);
        }
        #pragma unroll
        for (int msk = 1; msk < 16; msk <<= 1) rm = fmaxf(rm, __shfl_xor(rm, msk));
        float mnew = fmaxf(m_run[e], rm);
        float fac = __expf(m_run[e] - mnew);
        float rs = 0.f;
        #pragma unroll
        for (int ct = 0; ct < 4; ++ct) {
          float pv = (sv[ct] > -1e29f) ? __expf(sv[ct] - mnew) : 0.f;
          rs += pv;
          Ps[wv][lg*4 + e][ct*16 + lr] = f2bf(pv);
        }
        #pragma unroll
        for (int msk = 1; msk < 16; msk <<= 1) rs += __shfl_xor(rs, msk);
        l_sum[e] = l_sum[e] * fac + rs;
        m_run[e] = mnew;
        #pragma unroll
        for (int nt = 0; nt < 8; ++nt) o[nt][e] *= fac;
      }
      asm volatile("s_waitcnt lgkmcnt(0)" ::: "memory");
      #pragma unroll
      for (int kk = 0; kk < 2; ++kk) {
        bf16x8 pf = *(const bf16x8*)((const char*)&Ps[wv][lr][0] + kk*64 + lg*16);
        #pragma unroll
        for (int nt = 0; nt < 8; ++nt) {
          bf16x8 vf = *(const bf16x8*)((const char*)&Vs[nt*16 + lr][0] + kk*64 + lg*16);
          o[nt] = __builtin_amdgcn_mfma_f32_16x16x32_bf16(pf, vf, o[nt], 0, 0, 0);
        }
      }
    }
    __syncthreads();
  }

  #pragma unroll
  for (int nt = 0; nt < 8; ++nt) {
    #pragma unroll
    for (int e = 0; e < 4; ++e) {
      int t = q0 + wv*16 + lg*4 + e;
      int d = nt*16 + lr;
      y[(size_t)(b*T_ + t) * C_ + h*D_ + d] = f2bf(o[nt][e] / l_sum[e]);
    }
  }
}

extern "C" void kernel_launch(void* const* d_in, const int* in_sizes, int n_in,
                              void* d_out, int out_size, void* d_ws, size_t ws_size,
                              hipStream_t stream) {
  const float* x      = (const float*)d_in[0];
  const float* fcos   = (const float*)d_in[1];
  const float* fsin   = (const float*)d_in[2];
  const float* w_attn = (const float*)d_in[3];
  const float* w_proj = (const float*)d_in[4];
  float* out = (float*)d_out;

  char* ws = (char*)d_ws;
  unsigned short* x_bf = (unsigned short*)(ws);
  unsigned short* wa_t = (unsigned short*)(ws + 16777216ull);
  unsigned short* wp_t = (unsigned short*)(ws + 41943040ull);
  unsigned short* qkv  = (unsigned short*)(ws + 50331648ull);
  unsigned short* q_r  = (unsigned short*)(ws + 100663296ull);
  unsigned short* k_r  = (unsigned short*)(ws + 117440512ull);
  unsigned short* v_t  = (unsigned short*)(ws + 134217728ull);
  unsigned short* y_bf = x_bf;

  k_cvt<<<dim3(4096), dim3(256), 0, stream>>>(x, x_bf, M_*C_);
  k_tcvt<<<dim3(192, 64), dim3(256), 0, stream>>>(w_attn, wa_t, C_, N1_);
  k_tcvt<<<dim3(64, 64), dim3(256), 0, stream>>>(w_proj, wp_t, C_, C_);
  k_gemm8<false><<<dim3(384), dim3(512), 0, stream>>>(x_bf, wa_t, qkv, N1_, C_);
  k_reorg<<<dim3(32, 32), dim3(256), 0, stream>>>(qkv, fcos, fsin, q_r, k_r, v_t);
  k_attn<<<dim3(32, 32), dim3(256), 0, stream>>>(q_r, k_r, v_t, y_bf);
  k_gemm8<true><<<dim3(128), dim3(512), 0, stream>>>(y_bf, wp_t, out, C_, C_);
}

// Round 5
// 304.265 us; speedup vs baseline: 1.1417x; 1.0253x over previous
//
#include <hip/hip_runtime.h>
#include <stdint.h>

#define B_ 2
#define T_ 2048
#define C_ 2048
#define H_ 16
#define D_ 128
#define W_ 512
#define M_ (B_*T_)      // 4096
#define N1_ (3*C_)      // 6144

typedef short bf16x8 __attribute__((ext_vector_type(8)));
typedef unsigned short u16x8 __attribute__((ext_vector_type(8)));
typedef float f32x4 __attribute__((ext_vector_type(4)));

#define SGB __builtin_amdgcn_sched_group_barrier

__device__ __forceinline__ unsigned short f2bf(float f) {
  union { float f; unsigned u; } v; v.f = f;
  unsigned r = v.u + 0x7fffu + ((v.u >> 16) & 1u);
  return (unsigned short)(r >> 16);
}
__device__ __forceinline__ float bf2f(unsigned short b) {
  union { unsigned u; float f; } v; v.u = ((unsigned)b) << 16;
  return v.f;
}

__device__ __forceinline__ void gload_lds16(const void* g, void* l) {
  __builtin_amdgcn_global_load_lds((const __attribute__((address_space(1))) void*)g,
                                   (__attribute__((address_space(3))) void*)l, 16, 0, 0);
}

// ---------- fp32 -> bf16 convert ----------
__global__ void k_cvt(const float* __restrict__ s, unsigned short* __restrict__ d, int n) {
  int i = (blockIdx.x * blockDim.x + threadIdx.x) * 8;
  if (i >= n) return;
  float4 a = *(const float4*)(s + i);
  float4 b = *(const float4*)(s + i + 4);
  u16x8 o;
  o[0]=f2bf(a.x); o[1]=f2bf(a.y); o[2]=f2bf(a.z); o[3]=f2bf(a.w);
  o[4]=f2bf(b.x); o[5]=f2bf(b.y); o[6]=f2bf(b.z); o[7]=f2bf(b.w);
  *(u16x8*)(d + i) = o;
}

// ---------- transpose + convert: src [R][Cc] f32 -> dst [Cc][R] bf16 ----------
__global__ void k_tcvt(const float* __restrict__ s, unsigned short* __restrict__ d, int R, int Cc) {
  __shared__ float tile[32][33];
  int c0 = blockIdx.x * 32, r0 = blockIdx.y * 32;
  int tx = threadIdx.x & 31, ty = threadIdx.x >> 5;
  #pragma unroll
  for (int j = 0; j < 32; j += 8) tile[ty + j][tx] = s[(size_t)(r0 + ty + j) * Cc + c0 + tx];
  __syncthreads();
  #pragma unroll
  for (int j = 0; j < 32; j += 8) d[(size_t)(c0 + ty + j) * R + r0 + tx] = f2bf(tile[tx][ty + j]);
}

// ---------- 256xBN 4-phase GEMM, reg-pipelined + SGB-interleaved ds_reads ----------
// LDS: [parity][khalf][rows][32 k] bf16, st_16x32 XOR swizzle.
// Phase k's MFMA consumes fragments loaded during phase k-1's cluster; the
// next-phase ds_reads are interleaved INTO the MFMA cluster via
// sched_group_barrier ([MFMA*2, DS_READ*1] groups) so LDS drain overlaps MFMA.
// Hazard ledger identical to round 4 (reads moved earlier within same phase,
// still after the phase-start barrier):
//   ph0 reads Ya=A[p][0]r4-7; ph1 reads Xa=A[p][1]r0-3,Xb=B[p][1];
//   ph2 reads Ya=A[p][1]r4-7; ph3 reads Xa=A[p^1][0]r0-3,Xb=B[p^1][0].
//   Stages: ph0->A[p^1][1](t+1), ph1->B[p][0](t+2), ph2->A[p][0](t+2),
//   ph3->B[p][1](t+2); each follows a barrier postdating its readers' drain.
//   ph3 vmcnt covers all of tile t+1 (youngest = t+1.A1 @ t.ph0; younger
//   ticks = t+2.B0 + t+2.A0 = 2+BT); tail (t>=NT-2) uses vmcnt(0).
template<int ROWS>
__device__ __forceinline__ void stage_half(const unsigned short* __restrict__ gbase,
                                           int row0, int K, int kt, int kh,
                                           unsigned short* region, int tid, int sw) {
  const char* gsrc = (const char*)(gbase + (size_t)row0 * K + kt * 64 + kh * 32);
  {
    int o = tid * 16, s = o ^ sw;
    gload_lds16(gsrc + (size_t)(s >> 6) * (K * 2) + (s & 63), (char*)region + o);
  }
  if (ROWS == 256) {
    int o = (512 + tid) * 16, s = o ^ sw;
    gload_lds16(gsrc + (size_t)(s >> 6) * (K * 2) + (s & 63), (char*)region + o);
  }
}

template<int BN, bool F32OUT>
__global__ __launch_bounds__(512, 2) void k_gemm8(const unsigned short* __restrict__ A,
                                                  const unsigned short* __restrict__ Bt,
                                                  void* __restrict__ Cp,
                                                  int Ntot, int K) {
  constexpr int NBF = BN / 64;            // B fragments per wave (4 or 2)
  constexpr int BROWS = (BN == 256) ? 256 : 128;
  __shared__ unsigned short As[2][2][256 * 32];
  __shared__ unsigned short Bs[2][2][BN * 32];
  const int tid = threadIdx.x, lane = tid & 63, wv = tid >> 6;
  const int wm = wv >> 2, wn = wv & 3;
  const int lr = lane & 15, lg = lane >> 4;
  const int sw = tid & 32;
  const int fofs = lr * 64 + ((lg * 16) ^ ((lr & 8) << 2));
  const int aoff = wm * 128 * 64 + fofs;
  const int boff = wn * (BN / 4) * 64 + fofs;

  const int nwg = gridDim.x;
  const int nbx = Ntot / BN;
  const int q = nwg >> 3, r = nwg & 7;
  const int xcd = blockIdx.x & 7, off = blockIdx.x >> 3;
  const int bid = (xcd < r ? xcd * (q + 1) : r * (q + 1) + (xcd - r) * q) + off;
  const int bm0 = (bid / nbx) << 8;
  const int bn0 = (bid % nbx) * BN;

  f32x4 acc[8][NBF];
  #pragma unroll
  for (int i = 0; i < 8; ++i)
    #pragma unroll
    for (int j = 0; j < NBF; ++j)
      #pragma unroll
      for (int e = 0; e < 4; ++e) acc[i][j][e] = 0.f;

  const int NT = K >> 6;

  stage_half<256  >(A,  bm0, K, 0, 0, As[0][0], tid, sw);
  stage_half<BROWS>(Bt, bn0, K, 0, 0, Bs[0][0], tid, sw);
  stage_half<BROWS>(Bt, bn0, K, 0, 1, Bs[0][1], tid, sw);
  stage_half<256  >(A,  bm0, K, 0, 1, As[0][1], tid, sw);
  stage_half<BROWS>(Bt, bn0, K, 1, 0, Bs[1][0], tid, sw);
  stage_half<256  >(A,  bm0, K, 1, 0, As[1][0], tid, sw);
  stage_half<BROWS>(Bt, bn0, K, 1, 1, Bs[1][1], tid, sw);
  asm volatile("s_waitcnt vmcnt(4)" ::: "memory");
  __builtin_amdgcn_s_barrier();

  bf16x8 Xa[4], Xb[NBF], Ya[4];
  #pragma unroll
  for (int j = 0; j < NBF; ++j) Xb[j] = *(const bf16x8*)((const char*)Bs[0][0] + boff + j * 1024);
  #pragma unroll
  for (int i = 0; i < 4; ++i) Xa[i] = *(const bf16x8*)((const char*)As[0][0] + aoff + i * 1024);

  #pragma unroll 2
  for (int t = 0; t < NT; ++t) {
    const int p = t & 1;
    const char* Ar0 = (const char*)As[p][0];
    const char* Ar1 = (const char*)As[p][1];
    const char* Br1 = (const char*)Bs[p][1];
    const char* ArN = (const char*)As[p ^ 1][0];
    const char* BrN = (const char*)Bs[p ^ 1][0];

    // ---- ph0: MFMA(acc0-3, Xa,Xb) ∥ read Ya=A[p][0]r4-7; stage (t+1).A1 ----
    asm volatile("s_waitcnt lgkmcnt(0)" ::: "memory");
    __builtin_amdgcn_sched_barrier(0);
    __builtin_amdgcn_s_setprio(1);
    #pragma unroll
    for (int j = 0; j < NBF; ++j)
      #pragma unroll
      for (int i = 0; i < 4; ++i)
        acc[i][j] = __builtin_amdgcn_mfma_f32_16x16x32_bf16(Xa[i], Xb[j], acc[i][j], 0, 0, 0);
    #pragma unroll
    for (int i = 0; i < 4; ++i) Ya[i] = *(const bf16x8*)(Ar0 + aoff + (i + 4) * 1024);
    #pragma unroll
    for (int g = 0; g < 2 * NBF; ++g) { SGB(0x8, 2, 0); if (g < 4) SGB(0x100, 1, 0); }
    __builtin_amdgcn_s_setprio(0);
    if (t + 1 < NT) stage_half<256>(A, bm0, K, t + 1, 1, As[p ^ 1][1], tid, sw);
    __builtin_amdgcn_s_barrier();

    // ---- ph1: MFMA(acc4-7, Ya,Xb) ∥ read Xa=A[p][1]r0-3, Xb=B[p][1]; stage (t+2).B0 ----
    asm volatile("s_waitcnt lgkmcnt(0)" ::: "memory");
    __builtin_amdgcn_sched_barrier(0);
    __builtin_amdgcn_s_setprio(1);
    #pragma unroll
    for (int j = 0; j < NBF; ++j)
      #pragma unroll
      for (int i = 0; i < 4; ++i)
        acc[i + 4][j] = __builtin_amdgcn_mfma_f32_16x16x32_bf16(Ya[i], Xb[j], acc[i + 4][j], 0, 0, 0);
    #pragma unroll
    for (int i = 0; i < 4; ++i) Xa[i] = *(const bf16x8*)(Ar1 + aoff + i * 1024);
    #pragma unroll
    for (int j = 0; j < NBF; ++j) Xb[j] = *(const bf16x8*)(Br1 + boff + j * 1024);
    #pragma unroll
    for (int g = 0; g < 2 * NBF; ++g) { SGB(0x8, 2, 0); if (g < 4 + NBF) SGB(0x100, 1, 0); }
    if (4 + NBF > 2 * NBF) SGB(0x100, 4 + NBF - 2 * NBF, 0);
    __builtin_amdgcn_s_setprio(0);
    if (t + 2 < NT) stage_half<BROWS>(Bt, bn0, K, t + 2, 0, Bs[p][0], tid, sw);
    __builtin_amdgcn_s_barrier();

    // ---- ph2: MFMA(acc0-3, Xa,Xb) ∥ read Ya=A[p][1]r4-7; stage (t+2).A0 ----
    asm volatile("s_waitcnt lgkmcnt(0)" ::: "memory");
    __builtin_amdgcn_sched_barrier(0);
    __builtin_amdgcn_s_setprio(1);
    #pragma unroll
    for (int j = 0; j < NBF; ++j)
      #pragma unroll
      for (int i = 0; i < 4; ++i)
        acc[i][j] = __builtin_amdgcn_mfma_f32_16x16x32_bf16(Xa[i], Xb[j], acc[i][j], 0, 0, 0);
    #pragma unroll
    for (int i = 0; i < 4; ++i) Ya[i] = *(const bf16x8*)(Ar1 + aoff + (i + 4) * 1024);
    #pragma unroll
    for (int g = 0; g < 2 * NBF; ++g) { SGB(0x8, 2, 0); if (g < 4) SGB(0x100, 1, 0); }
    __builtin_amdgcn_s_setprio(0);
    if (t + 2 < NT) stage_half<256>(A, bm0, K, t + 2, 0, As[p][0], tid, sw);
    __builtin_amdgcn_s_barrier();

    // ---- ph3: vmcnt; MFMA(acc4-7, Ya,Xb) ∥ read next-tile Xa,Xb; stage (t+2).B1 ----
    asm volatile("s_waitcnt lgkmcnt(0)" ::: "memory");
    __builtin_amdgcn_sched_barrier(0);
    if (t < NT - 2) {
      if (BN == 256) asm volatile("s_waitcnt vmcnt(4)" ::: "memory");
      else           asm volatile("s_waitcnt vmcnt(3)" ::: "memory");
    } else {
      asm volatile("s_waitcnt vmcnt(0)" ::: "memory");
    }
    __builtin_amdgcn_sched_barrier(0);
    __builtin_amdgcn_s_setprio(1);
    #pragma unroll
    for (int j = 0; j < NBF; ++j)
      #pragma unroll
      for (int i = 0; i < 4; ++i)
        acc[i + 4][j] = __builtin_amdgcn_mfma_f32_16x16x32_bf16(Ya[i], Xb[j], acc[i + 4][j], 0, 0, 0);
    #pragma unroll
    for (int i = 0; i < 4; ++i) Xa[i] = *(const bf16x8*)(ArN + aoff + i * 1024);
    #pragma unroll
    for (int j = 0; j < NBF; ++j) Xb[j] = *(const bf16x8*)(BrN + boff + j * 1024);
    #pragma unroll
    for (int g = 0; g < 2 * NBF; ++g) { SGB(0x8, 2, 0); if (g < 4 + NBF) SGB(0x100, 1, 0); }
    if (4 + NBF > 2 * NBF) SGB(0x100, 4 + NBF - 2 * NBF, 0);
    __builtin_amdgcn_s_setprio(0);
    if (t + 2 < NT) stage_half<BROWS>(Bt, bn0, K, t + 2, 1, Bs[p][1], tid, sw);
    __builtin_amdgcn_s_barrier();
  }
  asm volatile("s_waitcnt lgkmcnt(0)" ::: "memory");

  #pragma unroll
  for (int i = 0; i < 8; ++i)
    #pragma unroll
    for (int j = 0; j < NBF; ++j) {
      int m = bm0 + wm * 128 + i * 16 + lg * 4;
      int n = bn0 + wn * (BN / 4) + j * 16 + lr;
      #pragma unroll
      for (int e = 0; e < 4; ++e) {
        if (F32OUT) ((float*)Cp)[(size_t)(m + e) * Ntot + n] = acc[i][j][e];
        else ((unsigned short*)Cp)[(size_t)(m + e) * Ntot + n] = f2bf(acc[i][j][e]);
      }
    }
}

// ---------- reorg: RoPE(q,k) -> (B,H,T,D); v -> v_t (B,H,D,T) ----------
__global__ __launch_bounds__(256) void k_reorg(const unsigned short* __restrict__ qkv,
                        const float* __restrict__ fcos, const float* __restrict__ fsin,
                        unsigned short* __restrict__ q_r, unsigned short* __restrict__ k_r,
                        unsigned short* __restrict__ v_t) {
  const int bh = blockIdx.x, b = bh >> 4, h = bh & 15;
  const int t0 = blockIdx.y * 64;
  const int tid = threadIdx.x;
  __shared__ unsigned short vt[64][136];
  #pragma unroll
  for (int p = 0; p < 4; ++p) {
    int idx = p * 256 + tid;
    int tl = idx >> 4, sg = idx & 15;
    int t = t0 + tl, d0 = sg * 8;
    float sgn = (d0 < 64) ? -1.f : 1.f;
    float4 c0v = *(const float4*)(fcos + t * D_ + d0);
    float4 c1v = *(const float4*)(fcos + t * D_ + d0 + 4);
    float4 s0v = *(const float4*)(fsin + t * D_ + d0);
    float4 s1v = *(const float4*)(fsin + t * D_ + d0 + 4);
    float cs[8] = {c0v.x,c0v.y,c0v.z,c0v.w,c1v.x,c1v.y,c1v.z,c1v.w};
    float sn[8] = {s0v.x,s0v.y,s0v.z,s0v.w,s1v.x,s1v.y,s1v.z,s1v.w};
    #pragma unroll
    for (int w = 0; w < 2; ++w) {
      const unsigned short* src = qkv + (size_t)(b*T_ + t) * N1_ + w*C_ + h*D_;
      u16x8 a  = *(const u16x8*)(src + d0);
      u16x8 pr = *(const u16x8*)(src + (d0 ^ 64));
      u16x8 o;
      #pragma unroll
      for (int e = 0; e < 8; ++e)
        o[e] = f2bf(bf2f(a[e]) * cs[e] + sgn * bf2f(pr[e]) * sn[e]);
      unsigned short* dst = (w ? k_r : q_r) + (size_t)((b*H_ + h)*T_ + t) * D_ + d0;
      *(u16x8*)dst = o;
    }
    const unsigned short* vsrc = qkv + (size_t)(b*T_ + t) * N1_ + 2*C_ + h*D_ + d0;
    *(u16x8*)&vt[tl][d0] = *(const u16x8*)vsrc;
  }
  __syncthreads();
  #pragma unroll
  for (int p = 0; p < 4; ++p) {
    int idx = p * 256 + tid;
    int sg = idx & 7, d = idx >> 3;
    u16x8 o;
    #pragma unroll
    for (int e = 0; e < 8; ++e) o[e] = vt[sg*8 + e][d];
    *(u16x8*)(v_t + (size_t)((b*H_ + h)*D_ + d) * T_ + t0 + sg*8) = o;
  }
}

// ---------- sliding-window flash attention ----------
__global__ __launch_bounds__(256) void k_attn(const unsigned short* __restrict__ q_r,
                       const unsigned short* __restrict__ k_r,
                       const unsigned short* __restrict__ v_t,
                       unsigned short* __restrict__ y) {
  const int bh = blockIdx.x, b = bh >> 4, h = bh & 15;
  const int q0 = blockIdx.y * 64;
  const int tid = threadIdx.x, lane = tid & 63, wv = tid >> 6;
  const int lr = lane & 15, lg = lane >> 4;

  __shared__ unsigned short Ks[64][136];
  __shared__ unsigned short Vs[128][72];
  __shared__ unsigned short Ps[4][16][80];

  const size_t bhT = (size_t)(b*H_ + h) * T_;
  const unsigned short* qbase = q_r + (bhT + q0 + wv*16 + lr) * D_;
  bf16x8 qf[4];
  #pragma unroll
  for (int kk = 0; kk < 4; ++kk) qf[kk] = *(const bf16x8*)(qbase + kk*32 + lg*8);

  f32x4 o[8];
  #pragma unroll
  for (int i = 0; i < 8; ++i)
    #pragma unroll
    for (int e = 0; e < 4; ++e) o[i][e] = 0.f;
  float m_run[4], l_sum[4];
  #pragma unroll
  for (int e = 0; e < 4; ++e) { m_run[e] = -1e30f; l_sum[e] = 0.f; }

  const int i_min = q0 + wv*16, i_max = i_min + 15;
  int kt_lo = q0 - (W_ - 1); if (kt_lo < 0) kt_lo = 0; kt_lo &= ~63;
  const float scale = 0.08838834764831845f;

  for (int kt = kt_lo; kt < q0 + 64; kt += 64) {
    #pragma unroll
    for (int p = 0; p < 4; ++p) {
      int idx = p*256 + tid;
      int row = idx >> 4, sg = idx & 15;
      *(u16x8*)&Ks[row][sg*8] = *(const u16x8*)(k_r + (bhT + kt + row) * D_ + sg*8);
    }
    #pragma unroll
    for (int p = 0; p < 4; ++p) {
      int idx = p*256 + tid;
      int d = idx >> 3, sg = idx & 7;
      *(u16x8*)&Vs[d][sg*8] = *(const u16x8*)(v_t + ((size_t)(b*H_+h)*D_ + d) * T_ + kt + sg*8);
    }
    __syncthreads();

    if (kt <= i_max && kt + 63 >= i_min - (W_ - 1)) {
      f32x4 s[4];
      #pragma unroll
      for (int ct = 0; ct < 4; ++ct)
        #pragma unroll
        for (int e = 0; e < 4; ++e) s[ct][e] = 0.f;
      #pragma unroll
      for (int kk = 0; kk < 4; ++kk) {
        #pragma unroll
        for (int ct = 0; ct < 4; ++ct) {
          bf16x8 kf = *(const bf16x8*)((const char*)&Ks[ct*16 + lr][0] + kk*64 + lg*16);
          s[ct] = __builtin_amdgcn_mfma_f32_16x16x32_bf16(qf[kk], kf, s[ct], 0, 0, 0);
        }
      }
      #pragma unroll
      for (int e = 0; e < 4; ++e) {
        int i = i_min + lg*4 + e;
        float sv[4];
        float rm = -1e30f;
        #pragma unroll
        for (int ct = 0; ct < 4; ++ct) {
          int j = kt + ct*16 + lr;
          bool ok = (j <= i) && (j > i - W_);
          sv[ct] = ok ? s[ct][e] * scale : -1e30f;
          rm = fmaxf(rm, sv[ct]);
        }
        #pragma unroll
        for (int msk = 1; msk < 16; msk <<= 1) rm = fmaxf(rm, __shfl_xor(rm, msk));
        float mnew = fmaxf(m_run[e], rm);
        float fac = __expf(m_run[e] - mnew);
        float rs = 0.f;
        #pragma unroll
        for (int ct = 0; ct < 4; ++ct) {
          float pv = (sv[ct] > -1e29f) ? __expf(sv[ct] - mnew) : 0.f;
          rs += pv;
          Ps[wv][lg*4 + e][ct*16 + lr] = f2bf(pv);
        }
        #pragma unroll
        for (int msk = 1; msk < 16; msk <<= 1) rs += __shfl_xor(rs, msk);
        l_sum[e] = l_sum[e] * fac + rs;
        m_run[e] = mnew;
        #pragma unroll
        for (int nt = 0; nt < 8; ++nt) o[nt][e] *= fac;
      }
      asm volatile("s_waitcnt lgkmcnt(0)" ::: "memory");
      #pragma unroll
      for (int kk = 0; kk < 2; ++kk) {
        bf16x8 pf = *(const bf16x8*)((const char*)&Ps[wv][lr][0] + kk*64 + lg*16);
        #pragma unroll
        for (int nt = 0; nt < 8; ++nt) {
          bf16x8 vf = *(const bf16x8*)((const char*)&Vs[nt*16 + lr][0] + kk*64 + lg*16);
          o[nt] = __builtin_amdgcn_mfma_f32_16x16x32_bf16(pf, vf, o[nt], 0, 0, 0);
        }
      }
    }
    __syncthreads();
  }

  #pragma unroll
  for (int nt = 0; nt < 8; ++nt) {
    #pragma unroll
    for (int e = 0; e < 4; ++e) {
      int t = q0 + wv*16 + lg*4 + e;
      int d = nt*16 + lr;
      y[(size_t)(b*T_ + t) * C_ + h*D_ + d] = f2bf(o[nt][e] / l_sum[e]);
    }
  }
}

extern "C" void kernel_launch(void* const* d_in, const int* in_sizes, int n_in,
                              void* d_out, int out_size, void* d_ws, size_t ws_size,
                              hipStream_t stream) {
  const float* x      = (const float*)d_in[0];
  const float* fcos   = (const float*)d_in[1];
  const float* fsin   = (const float*)d_in[2];
  const float* w_attn = (const float*)d_in[3];
  const float* w_proj = (const float*)d_in[4];
  float* out = (float*)d_out;

  char* ws = (char*)d_ws;
  unsigned short* x_bf = (unsigned short*)(ws);
  unsigned short* wa_t = (unsigned short*)(ws + 16777216ull);
  unsigned short* wp_t = (unsigned short*)(ws + 41943040ull);
  unsigned short* qkv  = (unsigned short*)(ws + 50331648ull);
  unsigned short* q_r  = (unsigned short*)(ws + 100663296ull);
  unsigned short* k_r  = (unsigned short*)(ws + 117440512ull);
  unsigned short* v_t  = (unsigned short*)(ws + 134217728ull);
  unsigned short* y_bf = x_bf;

  k_cvt<<<dim3(4096), dim3(256), 0, stream>>>(x, x_bf, M_*C_);
  k_tcvt<<<dim3(192, 64), dim3(256), 0, stream>>>(w_attn, wa_t, C_, N1_);
  k_tcvt<<<dim3(64, 64), dim3(256), 0, stream>>>(w_proj, wp_t, C_, C_);
  k_gemm8<256, false><<<dim3(384), dim3(512), 0, stream>>>(x_bf, wa_t, qkv, N1_, C_);
  k_reorg<<<dim3(32, 32), dim3(256), 0, stream>>>(qkv, fcos, fsin, q_r, k_r, v_t);
  k_attn<<<dim3(32, 32), dim3(256), 0, stream>>>(q_r, k_r, v_t, y_bf);
  k_gemm8<128, true><<<dim3(256), dim3(512), 0, stream>>>(y_bf, wp_t, out, C_, C_);
}